// Round 8
// baseline (170.668 us; speedup 1.0000x reference)
//
#include <hip/hip_runtime.h>
#include <math.h>

#define T_ 2048
#define H_ 16

typedef __attribute__((ext_vector_type(8))) short bfx8;   // 8 bf16 = 4 VGPRs
typedef __attribute__((ext_vector_type(4))) float f32x4;  // MFMA accumulator

__device__ __forceinline__ short f2bf(float f) {
  union { float f; unsigned u; } x; x.f = f;
  unsigned r = (x.u + 0x7FFFu + ((x.u >> 16) & 1u)) >> 16;  // RNE
  return (short)r;
}
__device__ __forceinline__ float bf2f(short s) {
  union { unsigned u; float f; } x;
  x.u = ((unsigned)(unsigned short)s) << 16;
  return x.f;
}

#define GLD_LDS(g, l) \
  __builtin_amdgcn_global_load_lds( \
      (const __attribute__((address_space(1))) void*)(g), \
      (__attribute__((address_space(3))) void*)(l), 16, 0, 0)

// ---------------- prep: weight cvt + RMSNorm + Cb basis + tk table + Mt/H zero
__global__ __launch_bounds__(256) void prep_kernel(
    const float* __restrict__ Wk, const float* __restrict__ Wv,
    const float* __restrict__ Wo, const float* __restrict__ angles,
    const float* __restrict__ states, const float* __restrict__ ln_w,
    short* __restrict__ Wkb, short* __restrict__ Wvb, short* __restrict__ Wob,
    short* __restrict__ xb, short* __restrict__ Cb, short* __restrict__ tkT,
    float* __restrict__ MtH) {
  const int blk = blockIdx.x;
  if (blk < 3072) {
    const int i = blk * 256 + threadIdx.x;
    const int which = i >> 18;
    const int idx = i & 262143;
    const float* s = (which == 0) ? Wk : (which == 1) ? Wv : Wo;
    short* d = (which == 0) ? Wkb : (which == 1) ? Wvb : Wob;
    const float4 v = ((const float4*)s)[idx];
    short4 r;
    r.x = f2bf(v.x); r.y = f2bf(v.y); r.z = f2bf(v.z); r.w = f2bf(v.w);
    ((short4*)d)[idx] = r;
  } else if (blk < 7168) {
    const int row = blk - 3072;
    const int tid = threadIdx.x;
    const float4 v = ((const float4*)(states + (size_t)row * 1024))[tid];
    float ss = v.x * v.x + v.y * v.y + v.z * v.z + v.w * v.w;
#pragma unroll
    for (int off = 32; off >= 1; off >>= 1) ss += __shfl_xor(ss, off);
    __shared__ float red[4];
    if ((tid & 63) == 0) red[tid >> 6] = ss;
    __syncthreads();
    const float tot = red[0] + red[1] + red[2] + red[3];
    const float scale = rsqrtf(tot * (1.0f / 1024.0f) + 1.1920928955078125e-07f);
    const float4 w = ((const float4*)ln_w)[tid];
    short4 o;
    o.x = f2bf(v.x * scale * w.x);
    o.y = f2bf(v.y * scale * w.y);
    o.z = f2bf(v.z * scale * w.z);
    o.w = f2bf(v.w * scale * w.w);
    ((short4*)(xb + (size_t)row * 1024))[tid] = o;
  } else if (blk < 7424) {
    const int gid = (blk - 7168) * 256 + threadIdx.x;  // 64K: (t,j)
    const int j = gid & 31;
    const int t = gid >> 5;
    float s, c;
    sincosf((float)t * angles[j], &s, &c);
    Cb[(size_t)t * 64 + j] = f2bf(0.125f * c);
    Cb[(size_t)t * 64 + 32 + j] = f2bf(0.125f * s);
  } else if (blk < 7456) {
    const int gid = (blk - 7424) * 256 + threadIdx.x;  // 8K: (j, l-chunk)
    const int tc = gid & 255;
    const int j = gid >> 8;
    const float th = angles[j];
    short lo[8], hi[8];
#pragma unroll
    for (int r = 0; r < 8; ++r) {
      float s, c;
      sincosf((float)(tc * 8 + r) * th, &s, &c);
      lo[r] = f2bf((c + s) * 0.125f);
      hi[r] = f2bf((c - s) * 0.125f);
    }
    short* base = tkT + (size_t)j * 2048 + tc * 8;
    *(short4*)(base) = *(short4*)&lo[0];
    *(short4*)(base + 4) = *(short4*)&lo[4];
    short* base2 = tkT + (size_t)(32 + j) * 2048 + tc * 8;
    *(short4*)(base2) = *(short4*)&hi[0];
    *(short4*)(base2 + 4) = *(short4*)&hi[4];
  } else {  // zero Mt (512 KB) + H (512 KB): 65536 float4s
    const int gid = (blk - 7456) * 256 + threadIdx.x;
    ((float4*)MtH)[gid] = make_float4(0.f, 0.f, 0.f, 0.f);
  }
}

// ------- fused K+V GEMM + masked softmax + kv + Mt accumulation -------------
// 64 rows x 1 head per block -> 1024 blocks (4/CU, 4 waves/SIMD) for latency
// hiding. Waves 0/1: K cols 0-31/32-63; waves 2/3: V. Cross-wave softmax via
// redM/redS LDS tables. BK=64 + XOR-8 swizzle as in round 7.
__global__ __launch_bounds__(256) void kvgemm_kernel(
    const short* __restrict__ xb, const short* __restrict__ Wkb,
    const short* __restrict__ Wvb, const float* __restrict__ bk,
    const float* __restrict__ bv, const int* __restrict__ mask,
    const short* __restrict__ tkT, float* __restrict__ Mt) {
  __shared__ short smem[12288];  // As[64][64] | Bk[64][64] | Bv[64][64] 24KB
  __shared__ float redM[2][64];
  __shared__ float redS[2][64];
  short(*As)[64] = (short(*)[64])smem;
  short(*Bk)[64] = (short(*)[64])(smem + 4096);
  short(*Bv)[64] = (short(*)[64])(smem + 8192);
  short(*Vs)[64] = (short(*)[64])smem;            // overlay As post-loop
  short(*kvS)[68] = (short(*)[68])(smem + 4096);  // overlay Bk+Bv (8.5KB<16KB)

  const int row0 = blockIdx.x * 64;  // XCD = x%8
  const int h = blockIdx.y;
  const int t = threadIdx.x;
  const int lane = t & 63;
  const int wv = t >> 6;
  const bool isV = wv >= 2;
  const int whalf = wv & 1;          // col half within the 64-wide head
  const int lrow = lane & 15;
  const int quad = lane >> 4;

  // staging: thread t owns phys slot t&7 of row t>>3 (+32); fetches k-slot
  // (t&7)^(row&7). LDS dest is lane-contiguous (DMA constraint).
  const int srow8 = t >> 3;
  const int kslotS = (t & 7) ^ (srow8 & 7);
  const short* gaS = xb + (size_t)(row0 + srow8) * 1024 + kslotS * 8;
  const short* gkS = Wkb + (size_t)(h * 64 + srow8) * 1024 + kslotS * 8;
  const short* gvS = Wvb + (size_t)(h * 64 + srow8) * 1024 + kslotS * 8;
  short* laS = &As[srow8][(t & 7) * 8];
  short* lkS = &Bk[srow8][(t & 7) * 8];
  short* lvS = &Bv[srow8][(t & 7) * 8];

  f32x4 acc[4][2] = {};
  for (int k0 = 0; k0 < 1024; k0 += 64) {
    GLD_LDS(gaS + k0, laS);
    GLD_LDS(gaS + 32 * 1024 + k0, laS + 2048);
    GLD_LDS(gkS + k0, lkS);
    GLD_LDS(gkS + 32 * 1024 + k0, lkS + 2048);
    GLD_LDS(gvS + k0, lvS);
    GLD_LDS(gvS + 32 * 1024 + k0, lvS + 2048);
    __syncthreads();
#pragma unroll
    for (int kk = 0; kk < 2; ++kk) {
      const int pcol = ((kk * 4 + quad) ^ (lrow & 7)) * 8;
      bfx8 af[4], bf_[2];
#pragma unroll
      for (int i = 0; i < 4; ++i)
        af[i] = *(const bfx8*)&As[i * 16 + lrow][pcol];
      const short(*Bs)[64] = isV ? Bv : Bk;
#pragma unroll
      for (int j = 0; j < 2; ++j)
        bf_[j] = *(const bfx8*)&Bs[whalf * 32 + j * 16 + lrow][pcol];
#pragma unroll
      for (int i = 0; i < 4; ++i)
#pragma unroll
        for (int j = 0; j < 2; ++j)
          acc[i][j] = __builtin_amdgcn_mfma_f32_16x16x32_bf16(af[i], bf_[j], acc[i][j], 0, 0, 0);
    }
    __syncthreads();
  }
  // phase A: V waves park V+bias in Vs; K waves bias+mask and half-row max
  if (isV) {
#pragma unroll
    for (int j = 0; j < 2; ++j) {
      const float bb = bv[h * 64 + whalf * 32 + j * 16 + lrow];
#pragma unroll
      for (int i = 0; i < 4; ++i)
#pragma unroll
        for (int rr = 0; rr < 4; ++rr)
          Vs[quad * 4 + i * 16 + rr][whalf * 32 + j * 16 + lrow] =
              f2bf(acc[i][j][rr] + bb);
    }
  } else {
    float bkc[2];
#pragma unroll
    for (int j = 0; j < 2; ++j) bkc[j] = bk[h * 64 + whalf * 32 + j * 16 + lrow];
#pragma unroll
    for (int i = 0; i < 4; ++i) {
#pragma unroll
      for (int rr = 0; rr < 4; ++rr) {
        const int row = quad * 4 + i * 16 + rr;
        const float m = (float)mask[row0 + row];
        const float k0v = (acc[i][0][rr] + bkc[0]) * m;
        const float k1v = (acc[i][1][rr] + bkc[1]) * m;
        acc[i][0][rr] = k0v;
        acc[i][1][rr] = k1v;
        float mx = fmaxf(k0v, k1v);
#pragma unroll
        for (int off = 8; off >= 1; off >>= 1) mx = fmaxf(mx, __shfl_xor(mx, off));
        if (lrow == 0) redM[whalf][row] = mx;
      }
    }
  }
  __syncthreads();
  // phase B: K waves exponentiate with global max, half-row sums
  if (!isV) {
#pragma unroll
    for (int i = 0; i < 4; ++i) {
#pragma unroll
      for (int rr = 0; rr < 4; ++rr) {
        const int row = quad * 4 + i * 16 + rr;
        const float mx = fmaxf(redM[0][row], redM[1][row]);
        const float e0 = expf(acc[i][0][rr] - mx);
        const float e1 = expf(acc[i][1][rr] - mx);
        acc[i][0][rr] = e0;
        acc[i][1][rr] = e1;
        float s = e0 + e1;
#pragma unroll
        for (int off = 8; off >= 1; off >>= 1) s += __shfl_xor(s, off);
        if (lrow == 0) redS[whalf][row] = s;
      }
    }
  }
  __syncthreads();
  // phase C: K waves normalize, multiply by V, write kvS[d][l]
  if (!isV) {
#pragma unroll
    for (int j = 0; j < 2; ++j) {
      const int d = whalf * 32 + j * 16 + lrow;
#pragma unroll
      for (int i = 0; i < 4; ++i) {
        short4 o;
        short* op = (short*)&o;
#pragma unroll
        for (int rr = 0; rr < 4; ++rr) {
          const int row = quad * 4 + i * 16 + rr;
          const float inv = 1.0f / (redS[0][row] + redS[1][row]);
          op[rr] = f2bf(acc[i][j][rr] * inv * bf2f(Vs[row][d]));
        }
        *(short4*)&kvS[d][quad * 4 + i * 16] = o;
      }
    }
  }
  __syncthreads();
  // Mt contraction: wave wv covers e in [wv*16, wv*16+16), K = 64 local l.
  const int bb = row0 >> 11;
  const int tb = row0 & 2047;
  const short* tkb = tkT + (size_t)(wv * 16 + lrow) * 2048 + tb;
  const int kg = quad * 8;
  f32x4 macc[4] = {};
#pragma unroll
  for (int kc = 0; kc < 2; ++kc) {
    const bfx8 af = *(const bfx8*)(tkb + kc * 32 + kg);
#pragma unroll
    for (int j = 0; j < 4; ++j) {
      const bfx8 bf_ = *(const bfx8*)&kvS[j * 16 + lrow][kc * 32 + kg];
      macc[j] = __builtin_amdgcn_mfma_f32_16x16x32_bf16(af, bf_, macc[j], 0, 0, 0);
    }
  }
  float* Mb = Mt + (size_t)(bb * 16 + h) * 4096;
#pragma unroll
  for (int j = 0; j < 4; ++j) {
    const int d = j * 16 + lrow;
#pragma unroll
    for (int rr = 0; rr < 4; ++rr) {
      const int e = wv * 16 + quad * 4 + rr;
      atomicAdd(&Mb[(size_t)e * 64 + d], macc[j][rr]);
    }
  }
}

// ---------------- fold: Mf[b][j][h*64+d]    = p*Mt[b,h][j][d] + q*Mt[b,h][32+j][d]
//                        Mf[b][32+j][h*64+d] = q*Mt[b,h][j][d] - p*Mt[b,h][32+j][d]
__global__ __launch_bounds__(256) void fold_kernel(
    const float* __restrict__ Mt, const float* __restrict__ angles,
    const float* __restrict__ delta, short* __restrict__ Mf) {
  const int bh = blockIdx.x;
  const int b = bh >> 4, h = bh & 15;
  const int t = threadIdx.x;
  const int j = t >> 3;
  const int d8 = (t & 7) * 8;
  float sphi, cphi;
  sincosf(delta[h] * angles[j], &sphi, &cphi);
  const float p = cphi + sphi, q = cphi - sphi;
  const float* m0 = Mt + (size_t)bh * 4096 + (size_t)j * 64 + d8;
  const float* m1 = Mt + (size_t)bh * 4096 + (size_t)(32 + j) * 64 + d8;
  short* oc = Mf + (size_t)b * 65536 + (size_t)j * 1024 + h * 64 + d8;
  short* os = Mf + (size_t)b * 65536 + (size_t)(32 + j) * 1024 + h * 64 + d8;
#pragma unroll
  for (int c = 0; c < 8; ++c) {
    const float a = m0[c], bb = m1[c];
    oc[c] = f2bf(p * a + q * bb);
    os[c] = f2bf(q * a - p * bb);
  }
}

// ---------------- H[b][o][kap] += sum_k Wob[o][k] * Mf[b][kap][k], split-K=8
__global__ __launch_bounds__(256) void hgemm_kernel(
    const short* __restrict__ Wob, const short* __restrict__ Mf,
    float* __restrict__ H) {
  const int kc = blockIdx.x;
  const int o0 = blockIdx.y * 64;
  const int b = blockIdx.z;
  const int t = threadIdx.x;
  const int lane = t & 63;
  const int w = t >> 6;
  const int lrow = lane & 15;
  const int kg = (lane >> 4) * 8;
  const int orow = o0 + w * 16 + lrow;
  f32x4 acc[4] = {};
#pragma unroll
  for (int it = 0; it < 4; ++it) {
    const int kb = kc * 128 + it * 32 + kg;
    const bfx8 af = *(const bfx8*)(Wob + (size_t)orow * 1024 + kb);
#pragma unroll
    for (int j = 0; j < 4; ++j) {
      const bfx8 bf_ = *(const bfx8*)(Mf + (size_t)b * 65536 +
                                      (size_t)(j * 16 + lrow) * 1024 + kb);
      acc[j] = __builtin_amdgcn_mfma_f32_16x16x32_bf16(af, bf_, acc[j], 0, 0, 0);
    }
  }
  float* Hb = H + (size_t)b * 65536;
#pragma unroll
  for (int j = 0; j < 4; ++j) {
    const int kap = j * 16 + lrow;
#pragma unroll
    for (int rr = 0; rr < 4; ++rr) {
      const int o = o0 + w * 16 + (lane >> 4) * 4 + rr;
      atomicAdd(&Hb[(size_t)o * 64 + kap], acc[j][rr]);
    }
  }
}

// ---------------- out[b][t][o] = sum_kap Cb[t][kap]*H[b][o][kap] + bo[o] ------
__global__ __launch_bounds__(256) void ofinal_kernel(
    const short* __restrict__ Cb, const float* __restrict__ H,
    const float* __restrict__ bo, float* __restrict__ out) {
  const int col0 = blockIdx.x * 128;
  const int row0 = blockIdx.y * 128;
  const int b = blockIdx.z;
  float* C = out + (size_t)b * 2097152;
  const float* Hb = H + (size_t)b * 65536;
  const int t = threadIdx.x;
  const int lane = t & 63;
  const int wv = t >> 6;
  const int wm = (wv & 1) * 64, wn = (wv >> 1) * 64;
  const int lrow = lane & 15;
  const int kg = (lane >> 4) * 8;
  f32x4 acc[4][4] = {};
#pragma unroll
  for (int k0 = 0; k0 < 64; k0 += 32) {
    bfx8 af[4], bf_[4];
#pragma unroll
    for (int i = 0; i < 4; ++i)
      af[i] = *(const bfx8*)(Cb + (size_t)(row0 + wm + i * 16 + lrow) * 64 + k0 + kg);
#pragma unroll
    for (int j = 0; j < 4; ++j) {
      const float* hp = Hb + (size_t)(col0 + wn + j * 16 + lrow) * 64 + k0 + kg;
      const float4 h0 = *(const float4*)hp;
      const float4 h1 = *(const float4*)(hp + 4);
      bfx8 bb;
      bb[0] = f2bf(h0.x); bb[1] = f2bf(h0.y); bb[2] = f2bf(h0.z); bb[3] = f2bf(h0.w);
      bb[4] = f2bf(h1.x); bb[5] = f2bf(h1.y); bb[6] = f2bf(h1.z); bb[7] = f2bf(h1.w);
      bf_[j] = bb;
    }
#pragma unroll
    for (int i = 0; i < 4; ++i)
#pragma unroll
      for (int j = 0; j < 4; ++j)
        acc[i][j] = __builtin_amdgcn_mfma_f32_16x16x32_bf16(af[i], bf_[j], acc[i][j], 0, 0, 0);
  }
  const int rq = (lane >> 4) * 4;
#pragma unroll
  for (int j = 0; j < 4; ++j) {
    const int c = col0 + wn + j * 16 + lrow;
    const float bb = bo[c];
#pragma unroll
    for (int i = 0; i < 4; ++i) {
      const int r = row0 + wm + i * 16 + rq;
#pragma unroll
      for (int rr = 0; rr < 4; ++rr)
        C[(size_t)(r + rr) * 1024 + c] = acc[i][j][rr] + bb;
    }
  }
}

extern "C" void kernel_launch(void* const* d_in, const int* in_sizes, int n_in,
                              void* d_out, int out_size, void* d_ws, size_t ws_size,
                              hipStream_t stream) {
  (void)in_sizes; (void)n_in; (void)out_size; (void)ws_size;
  const float* states = (const float*)d_in[0];
  const int* mask = (const int*)d_in[1];
  const float* ln_w = (const float*)d_in[2];
  const float* angles = (const float*)d_in[3];
  const float* delta = (const float*)d_in[4];
  // d_in[5]=Wq, d_in[6]=q_bias provably unused (softmax row-sums are 1).
  const float* Wk = (const float*)d_in[7];
  const float* bk = (const float*)d_in[8];
  const float* Wv = (const float*)d_in[9];
  const float* bv = (const float*)d_in[10];
  const float* Wo = (const float*)d_in[11];
  const float* bo = (const float*)d_in[12];
  float* out = (float*)d_out;

  char* W = (char*)d_ws;
  short* xb  = (short*)(W);                        // 8 MB   [4096][1024]
  short* Wkb = (short*)(W + (8u << 20));           // 2 MB
  short* Wvb = (short*)(W + (10u << 20));          // 2 MB
  short* Wob = (short*)(W + (12u << 20));          // 2 MB
  short* Cb  = (short*)(W + (14u << 20));          // 256 KB [2048][64]
  short* tkT = (short*)(W + (14u << 20) + (256u << 10));  // 256 KB [64][2048]
  short* Mf  = (short*)(W + (14u << 20) + (512u << 10));  // 256 KB [2][64][1024]
  float* Mt  = (float*)(W + (15u << 20));          // 512 KB [32][64][64]
  float* H   = (float*)(W + (15u << 20) + (512u << 10));  // 512 KB [2][1024][64]

  prep_kernel<<<7712, 256, 0, stream>>>(Wk, Wv, Wo, angles, states, ln_w,
                                        Wkb, Wvb, Wob, xb, Cb, tkT, Mt);
  kvgemm_kernel<<<dim3(64, 16), 256, 0, stream>>>(xb, Wkb, Wvb, bk, bv, mask,
                                                  tkT, Mt);
  fold_kernel<<<32, 256, 0, stream>>>(Mt, angles, delta, Mf);
  hgemm_kernel<<<dim3(8, 16, 2), 256, 0, stream>>>(Wob, Mf, H);
  ofinal_kernel<<<dim3(8, 16, 2), 256, 0, stream>>>(Cb, H, bo, out);
}